// Round 1
// baseline (1819.018 us; speedup 1.0000x reference)
//
#include <hip/hip_runtime.h>

#define N_NODES 100000
#define N_EDGES 1600000
#define N_GRAPHS 1000

// -------- scatter: agg[dst[e]*C + c] += h[src[e]*C + c] --------
// One thread per (edge, channel). Consecutive threads share an edge ->
// src/dst loads are broadcast; gather and atomicAdd are coalesced per wave.
template<int C>
__global__ __launch_bounds__(256) void scatter_add_kernel(
    const float* __restrict__ h,
    const int* __restrict__ src,
    const int* __restrict__ dst,
    float* __restrict__ agg)
{
    int tid = blockIdx.x * 256 + threadIdx.x;
    const int total = N_EDGES * C;
    if (tid >= total) return;
    int c = tid & (C - 1);
    int e = tid / C;            // C is a power of two -> compiler emits shift
    int s = src[e];
    int d = dst[e];
    atomicAdd(&agg[d * C + c], h[s * C + c]);
}

// -------- dense: hout = relu(((1+eps)*hin + agg) @ W + b) --------
// block = 256 threads = 4 nodes x 64 output channels.
// t rows staged in LDS (same-address broadcast across the 64 lanes of a node).
// W[k*64+j]: lane j reads consecutive floats -> coalesced, L1-resident.
template<int IN>
__global__ __launch_bounds__(256) void gin_dense_kernel(
    const float* __restrict__ hin,   // [N, IN]
    const float* __restrict__ agg,   // [N, IN]
    const float* __restrict__ W,     // [IN, 64] row-major
    const float* __restrict__ b,     // [64]
    const float* __restrict__ eps_p, // [1]
    float* __restrict__ hout)        // [N, 64]
{
    __shared__ float t[4][IN];
    const float ep1 = 1.0f + eps_p[0];
    const int node0 = blockIdx.x * 4;
    const int tidx  = threadIdx.x;

    // stage (1+eps)*hin + agg for 4 nodes
    for (int i = tidx; i < 4 * IN; i += 256) {
        int n = i / IN, k = i % IN;
        int node = node0 + n;
        float v = 0.0f;
        if (node < N_NODES) {
            int idx = node * IN + k;
            v = fmaf(ep1, hin[idx], agg[idx]);
        }
        t[n][k] = v;
    }
    __syncthreads();

    const int n = tidx >> 6;
    const int j = tidx & 63;
    const int node = node0 + n;
    if (node >= N_NODES) return;

    float acc = b[j];
#pragma unroll
    for (int k = 0; k < IN; ++k)
        acc = fmaf(t[n][k], W[k * 64 + j], acc);

    hout[node * 64 + j] = fmaxf(acc, 0.0f);
}

// -------- pool: sums[batch[i]] += h3[i], cnts[batch[i]] += 1 --------
__global__ __launch_bounds__(256) void pool_kernel(
    const float* __restrict__ h,     // [N, 64]
    const int* __restrict__ batch,   // [N]
    float* __restrict__ sums,        // [G, 64]
    float* __restrict__ cnts)        // [G]
{
    int tid = blockIdx.x * 256 + threadIdx.x;
    if (tid >= N_NODES * 64) return;
    int c = tid & 63;
    int i = tid >> 6;
    int g = batch[i];
    atomicAdd(&sums[g * 64 + c], h[i * 64 + c]);
    if (c == 0) atomicAdd(&cnts[g], 1.0f);
}

// -------- head: out[g] = relu(pooled @ Wf + bf) @ Wl + bl --------
__global__ __launch_bounds__(256) void head_kernel(
    const float* __restrict__ sums,  // [G, 64]
    const float* __restrict__ cnts,  // [G]
    const float* __restrict__ Wf,    // [64, 10]
    const float* __restrict__ bfv,   // [10]
    const float* __restrict__ Wl,    // [10]
    const float* __restrict__ blv,   // [1]
    float* __restrict__ out)         // [G]
{
    int g = blockIdx.x * 256 + threadIdx.x;
    if (g >= N_GRAPHS) return;
    float inv = 1.0f / fmaxf(cnts[g], 1.0f);
    float pooled[64];
#pragma unroll
    for (int k = 0; k < 64; ++k) pooled[k] = sums[g * 64 + k] * inv;
    float acc = blv[0];
#pragma unroll
    for (int j = 0; j < 10; ++j) {
        float s = bfv[j];
#pragma unroll
        for (int k = 0; k < 64; ++k) s = fmaf(pooled[k], Wf[k * 10 + j], s);
        acc = fmaf(fmaxf(s, 0.0f), Wl[j], acc);
    }
    out[g] = acc;
}

extern "C" void kernel_launch(void* const* d_in, const int* in_sizes, int n_in,
                              void* d_out, int out_size, void* d_ws, size_t ws_size,
                              hipStream_t stream)
{
    const float* x     = (const float*)d_in[0];
    const int*   ei    = (const int*)  d_in[1];
    const int*   src   = ei;                 // edge_index[0]
    const int*   dst   = ei + N_EDGES;       // edge_index[1]
    const int*   batch = (const int*)  d_in[2];
    const float* W1    = (const float*)d_in[3];
    const float* b1    = (const float*)d_in[4];
    const float* W2    = (const float*)d_in[5];
    const float* b2    = (const float*)d_in[6];
    const float* W3    = (const float*)d_in[7];
    const float* b3    = (const float*)d_in[8];
    const float* Wf    = (const float*)d_in[9];
    const float* bfv   = (const float*)d_in[10];
    const float* Wl    = (const float*)d_in[11];
    const float* blv   = (const float*)d_in[12];
    const float* eps1  = (const float*)d_in[13];
    const float* eps2  = (const float*)d_in[14];
    const float* eps3  = (const float*)d_in[15];

    // workspace layout (floats):
    //   agg  : N*128              (reused, only N*64 used for layers 2/3)
    //   h1   : N*64               (reused as h3)
    //   h2   : N*64
    //   sums : G*64
    //   cnts : G
    float* ws   = (float*)d_ws;
    float* agg  = ws;
    float* h1   = ws + N_NODES * 128;
    float* h2   = h1 + N_NODES * 64;
    float* h3   = h1;   // h1 dead once h2 is computed
    float* sums = h2 + N_NODES * 64;
    float* cnts = sums + N_GRAPHS * 64;

    // ---- layer 1 (IN=128) ----
    hipMemsetAsync(agg, 0, sizeof(float) * N_NODES * 128, stream);
    {
        const int total = N_EDGES * 128;
        scatter_add_kernel<128><<<(total + 255) / 256, 256, 0, stream>>>(x, src, dst, agg);
        gin_dense_kernel<128><<<(N_NODES + 3) / 4, 256, 0, stream>>>(x, agg, W1, b1, eps1, h1);
    }

    // ---- layer 2 (IN=64) ----
    hipMemsetAsync(agg, 0, sizeof(float) * N_NODES * 64, stream);
    {
        const int total = N_EDGES * 64;
        scatter_add_kernel<64><<<(total + 255) / 256, 256, 0, stream>>>(h1, src, dst, agg);
        gin_dense_kernel<64><<<(N_NODES + 3) / 4, 256, 0, stream>>>(h1, agg, W2, b2, eps2, h2);
    }

    // ---- layer 3 (IN=64) ----
    hipMemsetAsync(agg, 0, sizeof(float) * N_NODES * 64, stream);
    {
        const int total = N_EDGES * 64;
        scatter_add_kernel<64><<<(total + 255) / 256, 256, 0, stream>>>(h2, src, dst, agg);
        gin_dense_kernel<64><<<(N_NODES + 3) / 4, 256, 0, stream>>>(h2, agg, W3, b3, eps3, h3);
    }

    // ---- global mean pool + head ----
    hipMemsetAsync(sums, 0, sizeof(float) * (N_GRAPHS * 64 + N_GRAPHS), stream);
    pool_kernel<<<(N_NODES * 64 + 255) / 256, 256, 0, stream>>>(h3, batch, sums, cnts);
    head_kernel<<<(N_GRAPHS + 255) / 256, 256, 0, stream>>>(sums, cnts, Wf, bfv, Wl, blv,
                                                            (float*)d_out);
}

// Round 2
// 701.199 us; speedup vs baseline: 2.5942x; 2.5942x over previous
//
#include <hip/hip_runtime.h>

#define N_NODES 100000
#define N_EDGES 1600000
#define N_GRAPHS 1000
#define SCAN_B 1024
#define SCAN_NB ((N_NODES + SCAN_B - 1) / SCAN_B)   // 98

// ---------- CSR build: histogram of dst ----------
__global__ __launch_bounds__(256) void hist_kernel(
    const int* __restrict__ dst, int* __restrict__ deg)
{
    int e = blockIdx.x * 256 + threadIdx.x;
    if (e < N_EDGES) atomicAdd(&deg[dst[e]], 1);
}

// ---------- exclusive scan over deg (3 kernels) ----------
__global__ __launch_bounds__(256) void scan1_kernel(
    const int* __restrict__ deg, int* __restrict__ excl, int* __restrict__ bsum)
{
    __shared__ int s[256];
    int b = blockIdx.x, t = threadIdx.x;
    int base = b * SCAN_B + t * 4;
    int v[4];
#pragma unroll
    for (int i = 0; i < 4; ++i) v[i] = (base + i < N_NODES) ? deg[base + i] : 0;
    int tsum = v[0] + v[1] + v[2] + v[3];
    s[t] = tsum;
    __syncthreads();
    for (int off = 1; off < 256; off <<= 1) {
        int x = (t >= off) ? s[t - off] : 0;
        __syncthreads();
        s[t] += x;
        __syncthreads();
    }
    int run = s[t] - tsum;          // exclusive prefix of thread sums
#pragma unroll
    for (int i = 0; i < 4; ++i) {
        if (base + i < N_NODES) excl[base + i] = run;
        run += v[i];
    }
    if (t == 255) bsum[b] = s[255];
}

__global__ __launch_bounds__(128) void scan2_kernel(int* __restrict__ bsum)
{
    __shared__ int s[128];
    int t = threadIdx.x;
    int v = (t < SCAN_NB) ? bsum[t] : 0;
    s[t] = v;
    __syncthreads();
    for (int off = 1; off < 128; off <<= 1) {
        int x = (t >= off) ? s[t - off] : 0;
        __syncthreads();
        s[t] += x;
        __syncthreads();
    }
    if (t < SCAN_NB) bsum[t] = s[t] - v;   // exclusive
}

__global__ __launch_bounds__(256) void scan3_kernel(
    const int* __restrict__ excl, const int* __restrict__ bsum,
    int* __restrict__ row_off)
{
    int b = blockIdx.x, t = threadIdx.x;
    int add = bsum[b];
    int base = b * SCAN_B + t * 4;
#pragma unroll
    for (int i = 0; i < 4; ++i)
        if (base + i < N_NODES) row_off[base + i] = excl[base + i] + add;
    if (b == 0 && t == 0) row_off[N_NODES] = N_EDGES;
}

// ---------- bucket edges by dst ----------
__global__ __launch_bounds__(256) void bucket_kernel(
    const int* __restrict__ src, const int* __restrict__ dst,
    const int* __restrict__ row_off, int* __restrict__ cursor,
    int* __restrict__ esrc)
{
    int e = blockIdx.x * 256 + threadIdx.x;
    if (e >= N_EDGES) return;
    int d = dst[e];
    int pos = row_off[d] + atomicAdd(&cursor[d], 1);
    esrc[pos] = src[e];
}

// ---------- y = h @ W  (no bias; transform-before-aggregate) ----------
template<int IN>
__global__ __launch_bounds__(256) void gemm_kernel(
    const float* __restrict__ h,   // [N, IN]
    const float* __restrict__ W,   // [IN, 64]
    float* __restrict__ y)         // [N, 64]
{
    __shared__ float t4[4][IN];
    int node0 = blockIdx.x * 4;
    int t = threadIdx.x;
    for (int i = t; i < 4 * IN; i += 256) {
        int n = i / IN, k = i % IN;
        int node = node0 + n;
        t4[n][k] = (node < N_NODES) ? h[node * IN + k] : 0.0f;
    }
    __syncthreads();
    int n = t >> 6, j = t & 63;
    int node = node0 + n;
    if (node >= N_NODES) return;
    float acc = 0.0f;
#pragma unroll
    for (int k = 0; k < IN; ++k) acc = fmaf(t4[n][k], W[k * 64 + j], acc);
    y[node * 64 + j] = acc;
}

// ---------- CSR gather-sum + fused GIN epilogue ----------
// out[n] = relu((1+eps)*y[n] + sum_{e in seg(n)} y[esrc[e]] + b)
__global__ __launch_bounds__(256) void aggregate_kernel(
    const float* __restrict__ y,       // [N, 64]
    const int* __restrict__ row_off,   // [N+1]
    const int* __restrict__ esrc,      // [E]
    const float* __restrict__ b,       // [64]
    const float* __restrict__ eps_p,   // [1]
    float* __restrict__ out)           // [N, 64]
{
    int node = blockIdx.x * 4 + (threadIdx.x >> 6);
    int lane = threadIdx.x & 63;
    if (node >= N_NODES) return;
    int s0 = row_off[node], s1 = row_off[node + 1];
    float a0 = 0.f, a1 = 0.f, a2 = 0.f, a3 = 0.f;
    int e = s0;
    for (; e + 4 <= s1; e += 4) {
        int i0 = esrc[e], i1 = esrc[e + 1], i2 = esrc[e + 2], i3 = esrc[e + 3];
        a0 += y[i0 * 64 + lane];
        a1 += y[i1 * 64 + lane];
        a2 += y[i2 * 64 + lane];
        a3 += y[i3 * 64 + lane];
    }
    for (; e < s1; ++e) a0 += y[esrc[e] * 64 + lane];
    float agg = (a0 + a1) + (a2 + a3);
    float v = fmaf(1.0f + eps_p[0], y[node * 64 + lane], agg) + b[lane];
    out[node * 64 + lane] = fmaxf(v, 0.0f);
}

// ---------- mean-pool (sorted batch, binary search) + head MLP ----------
__global__ __launch_bounds__(256) void pool_head_kernel(
    const float* __restrict__ h,      // [N, 64]
    const int* __restrict__ batch,    // [N], sorted
    const float* __restrict__ Wf,     // [64, 10]
    const float* __restrict__ bfv,    // [10]
    const float* __restrict__ Wl,     // [10]
    const float* __restrict__ blv,    // [1]
    float* __restrict__ out)          // [G]
{
    __shared__ float red[4][64];
    __shared__ float pooled[64];
    __shared__ float hid[10];
    int g = blockIdx.x;
    int t = threadIdx.x;
    // binary search segment bounds (uniform across threads)
    int lo = 0, hi = N_NODES;
    while (lo < hi) { int mid = (lo + hi) >> 1; if (batch[mid] < g) lo = mid + 1; else hi = mid; }
    int start = lo;
    hi = N_NODES;
    while (lo < hi) { int mid = (lo + hi) >> 1; if (batch[mid] < g + 1) lo = mid + 1; else hi = mid; }
    int end = lo;

    int c = t & 63, nl = t >> 6;
    float acc = 0.0f;
    for (int i = start + nl; i < end; i += 4) acc += h[i * 64 + c];
    red[nl][c] = acc;
    __syncthreads();
    if (t < 64) {
        float cnt = (float)(end - start);
        float inv = 1.0f / fmaxf(cnt, 1.0f);
        pooled[t] = (red[0][t] + red[1][t] + red[2][t] + red[3][t]) * inv;
    }
    __syncthreads();
    if (t < 10) {
        float s = bfv[t];
#pragma unroll
        for (int k = 0; k < 64; ++k) s = fmaf(pooled[k], Wf[k * 10 + t], s);
        hid[t] = fmaxf(s, 0.0f);
    }
    __syncthreads();
    if (t == 0) {
        float s = blv[0];
#pragma unroll
        for (int j = 0; j < 10; ++j) s = fmaf(hid[j], Wl[j], s);
        out[g] = s;
    }
}

extern "C" void kernel_launch(void* const* d_in, const int* in_sizes, int n_in,
                              void* d_out, int out_size, void* d_ws, size_t ws_size,
                              hipStream_t stream)
{
    const float* x     = (const float*)d_in[0];
    const int*   ei    = (const int*)  d_in[1];
    const int*   src   = ei;               // edge_index[0]
    const int*   dst   = ei + N_EDGES;     // edge_index[1]
    const int*   batch = (const int*)  d_in[2];
    const float* W1    = (const float*)d_in[3];
    const float* b1    = (const float*)d_in[4];
    const float* W2    = (const float*)d_in[5];
    const float* b2    = (const float*)d_in[6];
    const float* W3    = (const float*)d_in[7];
    const float* b3    = (const float*)d_in[8];
    const float* Wf    = (const float*)d_in[9];
    const float* bfv   = (const float*)d_in[10];
    const float* Wl    = (const float*)d_in[11];
    const float* blv   = (const float*)d_in[12];
    const float* eps1  = (const float*)d_in[13];
    const float* eps2  = (const float*)d_in[14];
    const float* eps3  = (const float*)d_in[15];

    // ---- workspace layout ----
    float* y    = (float*)d_ws;                 // N*64
    float* h1   = y  + (size_t)N_NODES * 64;    // N*64 (also h3)
    float* h2   = h1 + (size_t)N_NODES * 64;    // N*64
    int*   ints = (int*)(h2 + (size_t)N_NODES * 64);
    int*   deg     = ints;                      // N      (zeroed)
    int*   cursor  = deg + N_NODES;             // N      (zeroed, adjacent -> one memset)
    int*   excl    = cursor + N_NODES;          // N
    int*   row_off = excl + N_NODES;            // N+1
    int*   bsum    = row_off + N_NODES + 1;     // 128
    int*   esrc    = bsum + 128;                // E

    // ---- build CSR (dst-sorted edge list) ----
    hipMemsetAsync(deg, 0, sizeof(int) * 2 * N_NODES, stream);  // deg + cursor
    hist_kernel<<<(N_EDGES + 255) / 256, 256, 0, stream>>>(dst, deg);
    scan1_kernel<<<SCAN_NB, 256, 0, stream>>>(deg, excl, bsum);
    scan2_kernel<<<1, 128, 0, stream>>>(bsum);
    scan3_kernel<<<SCAN_NB, 256, 0, stream>>>(excl, bsum, row_off);
    bucket_kernel<<<(N_EDGES + 255) / 256, 256, 0, stream>>>(src, dst, row_off, cursor, esrc);

    const int gblk = (N_NODES + 3) / 4;

    // ---- layer 1: y = x@W1 ; h1 = relu((1+e1)y + agg(y) + b1) ----
    gemm_kernel<128><<<gblk, 256, 0, stream>>>(x, W1, y);
    aggregate_kernel<<<gblk, 256, 0, stream>>>(y, row_off, esrc, b1, eps1, h1);

    // ---- layer 2 ----
    gemm_kernel<64><<<gblk, 256, 0, stream>>>(h1, W2, y);
    aggregate_kernel<<<gblk, 256, 0, stream>>>(y, row_off, esrc, b2, eps2, h2);

    // ---- layer 3 (reuse h1 as h3) ----
    gemm_kernel<64><<<gblk, 256, 0, stream>>>(h2, W3, y);
    aggregate_kernel<<<gblk, 256, 0, stream>>>(y, row_off, esrc, b3, eps3, h1);

    // ---- pool + head ----
    pool_head_kernel<<<N_GRAPHS, 256, 0, stream>>>(h1, batch, Wf, bfv, Wl, blv,
                                                   (float*)d_out);
}